// Round 4
// baseline (64.977 us; speedup 1.0000x reference)
//
#include <hip/hip_runtime.h>

#define NDIM 128   // feature dim D
#define NOUT 8     // output dim

// Kernel 1: per-node projection.
// P[n][0..7]   = h[n] . Wu[o]          (src half)
// P[n][8..15]  = h[n] . Wv[o] + b[o]   (dst half, bias baked in)
__global__ __launch_bounds__(256) void node_proj_kernel(
    const float* __restrict__ h, const float* __restrict__ W,
    const float* __restrict__ b, float* __restrict__ P, int n_nodes) {
  // Stage W into LDS as 16 rows of 32 float4 chunks:
  //   row o in [0,8)  : Wu[o] = W[o][0..127]
  //   row o in [8,16) : Wv[o-8] = W[o-8][128..255]
  __shared__ float4 Wl[16][32];
  const int t = threadIdx.x;
  for (int i = t; i < 16 * 32; i += 256) {
    const int o = i >> 5;        // 0..15
    const int j = i & 31;        // 0..31
    const int row = o & 7;
    const int half = o >> 3;     // 0 = Wu, 1 = Wv
    Wl[o][j] = reinterpret_cast<const float4*>(W + row * (2 * NDIM) + half * NDIM)[j];
  }
  __syncthreads();

  const int n = blockIdx.x * 256 + t;
  if (n >= n_nodes) return;

  const float4* __restrict__ hp =
      reinterpret_cast<const float4*>(h + (size_t)n * NDIM);

  float acc[16];
#pragma unroll
  for (int o = 0; o < 16; ++o) acc[o] = 0.0f;

#pragma unroll 4
  for (int j = 0; j < 32; ++j) {
    const float4 v = hp[j];
#pragma unroll
    for (int o = 0; o < 16; ++o) {
      // Wl address is wave-uniform -> LDS broadcast (conflict-free)
      const float4 w = Wl[o][j];
      acc[o] = fmaf(v.x, w.x,
               fmaf(v.y, w.y,
               fmaf(v.z, w.z,
               fmaf(v.w, w.w, acc[o]))));
    }
  }

  float4 r0, r1, r2, r3;
  r0.x = acc[0];  r0.y = acc[1];  r0.z = acc[2];  r0.w = acc[3];
  r1.x = acc[4];  r1.y = acc[5];  r1.z = acc[6];  r1.w = acc[7];
  // b is wave-uniform -> scalar loads
  r2.x = acc[8]  + b[0]; r2.y = acc[9]  + b[1]; r2.z = acc[10] + b[2]; r2.w = acc[11] + b[3];
  r3.x = acc[12] + b[4]; r3.y = acc[13] + b[5]; r3.z = acc[14] + b[6]; r3.w = acc[15] + b[7];

  float4* __restrict__ Pp = reinterpret_cast<float4*>(P + (size_t)n * 16);
  Pp[0] = r0; Pp[1] = r1; Pp[2] = r2; Pp[3] = r3;
}

// Kernel 2: per-edge gather + add. 32B gather per endpoint from the
// L2/L3-resident projection table; coalesced 32B/lane output store.
__global__ __launch_bounds__(256) void edge_score_kernel(
    const int* __restrict__ src, const int* __restrict__ dst,
    const float* __restrict__ P, float* __restrict__ out, int n_edges) {
  const int e = blockIdx.x * 256 + threadIdx.x;
  if (e >= n_edges) return;
  const int s = src[e];
  const int d = dst[e];

  const float4* __restrict__ Pp = reinterpret_cast<const float4*>(P);
  const float4 s0 = Pp[(size_t)s * 4 + 0];
  const float4 s1 = Pp[(size_t)s * 4 + 1];
  const float4 d0 = Pp[(size_t)d * 4 + 2];
  const float4 d1 = Pp[(size_t)d * 4 + 3];

  float4 r0, r1;
  r0.x = s0.x + d0.x; r0.y = s0.y + d0.y; r0.z = s0.z + d0.z; r0.w = s0.w + d0.w;
  r1.x = s1.x + d1.x; r1.y = s1.y + d1.y; r1.z = s1.z + d1.z; r1.w = s1.w + d1.w;

  float4* __restrict__ op = reinterpret_cast<float4*>(out + (size_t)e * NOUT);
  op[0] = r0;
  op[1] = r1;
}

// Fallback (only if workspace is too small): direct per-edge computation.
// Correct but gather-heavy (reads full h rows per edge).
__global__ __launch_bounds__(256) void edge_direct_kernel(
    const float* __restrict__ h, const int* __restrict__ src,
    const int* __restrict__ dst, const float* __restrict__ W,
    const float* __restrict__ b, float* __restrict__ out, int n_edges) {
  const int e = blockIdx.x * 256 + threadIdx.x;
  if (e >= n_edges) return;
  const int s = src[e];
  const int d = dst[e];
  const float4* __restrict__ hs = reinterpret_cast<const float4*>(h + (size_t)s * NDIM);
  const float4* __restrict__ hd = reinterpret_cast<const float4*>(h + (size_t)d * NDIM);
  const float4* __restrict__ W4 = reinterpret_cast<const float4*>(W);  // row = 64 float4

  float acc[NOUT];
#pragma unroll
  for (int o = 0; o < NOUT; ++o) acc[o] = b[o];

  for (int j = 0; j < 32; ++j) {
    const float4 vs = hs[j];
    const float4 vd = hd[j];
#pragma unroll
    for (int o = 0; o < NOUT; ++o) {
      const float4 wu = W4[o * 64 + j];        // Wu[o] chunk j
      const float4 wv = W4[o * 64 + 32 + j];   // Wv[o] chunk j
      acc[o] = fmaf(vs.x, wu.x, fmaf(vs.y, wu.y, fmaf(vs.z, wu.z, fmaf(vs.w, wu.w, acc[o]))));
      acc[o] = fmaf(vd.x, wv.x, fmaf(vd.y, wv.y, fmaf(vd.z, wv.z, fmaf(vd.w, wv.w, acc[o]))));
    }
  }

  float4 r0, r1;
  r0.x = acc[0]; r0.y = acc[1]; r0.z = acc[2]; r0.w = acc[3];
  r1.x = acc[4]; r1.y = acc[5]; r1.z = acc[6]; r1.w = acc[7];
  float4* __restrict__ op = reinterpret_cast<float4*>(out + (size_t)e * NOUT);
  op[0] = r0;
  op[1] = r1;
}

extern "C" void kernel_launch(void* const* d_in, const int* in_sizes, int n_in,
                              void* d_out, int out_size, void* d_ws, size_t ws_size,
                              hipStream_t stream) {
  const float* h   = (const float*)d_in[0];
  const int*   src = (const int*)d_in[1];
  const int*   dst = (const int*)d_in[2];
  const float* W   = (const float*)d_in[3];
  const float* b   = (const float*)d_in[4];
  float* out = (float*)d_out;

  const int n_nodes = in_sizes[0] / NDIM;
  const int n_edges = in_sizes[1];

  const size_t need = (size_t)n_nodes * 16 * sizeof(float);
  if (ws_size >= need) {
    float* P = (float*)d_ws;
    node_proj_kernel<<<(n_nodes + 255) / 256, 256, 0, stream>>>(h, W, b, P, n_nodes);
    edge_score_kernel<<<(n_edges + 255) / 256, 256, 0, stream>>>(src, dst, P, out, n_edges);
  } else {
    edge_direct_kernel<<<(n_edges + 255) / 256, 256, 0, stream>>>(h, src, dst, W, b, out, n_edges);
  }
}